// Round 7
// baseline (58.002 us; speedup 1.0000x reference)
//
#include <hip/hip_runtime.h>
#include <math.h>

// DTW loss: B=64, N=512, D=2, L1. Wave64 per batch, lane j owns cols [8j,8j+8).
// Round-7: identical to R6 EXCEPT the pairwise diff is forced to a single
// v_pk_add_f32 via inline asm (R6's f32x2 add scalarized to 2x v_add_f32 --
// clang doesn't form VOP3P f32 pk ops -- which is why R6 was flat vs R4).
// Steady step ~34 instr: 8 pk_add + 8 abs-add + 8 min3 + 8 add + dpp + ld.
// Single-variable experiment discriminating issue-cadence vs dep-latency.

typedef float f32x2 __attribute__((ext_vector_type(2)));

constexpr int NSEQ  = 512;
constexpr int BATCH = 64;
constexpr int LANES = 64;
constexpr int P     = 8;
constexpr int FRONT = 64;     // front pad (ramp reads row k-j < 0)
constexpr int XSN   = 656;    // max read idx = FRONT+584 = 648

__device__ __forceinline__ float dpp_wshr1_inf(float v) {
    // lane i <- lane i-1; lane 0 <- old = +inf (bound_ctrl=false)
    int r = __builtin_amdgcn_update_dpp(0x7F800000, __float_as_int(v),
                                        0x138, 0xF, 0xF, false);
    return __int_as_float(r);
}

__device__ __forceinline__ f32x2 pk_add(f32x2 a, f32x2 b) {
    f32x2 d;
    asm("v_pk_add_f32 %0, %1, %2" : "=v"(d) : "v"(a), "v"(b));
    return d;
}

__global__ __launch_bounds__(LANES) void dtw_fused(
    const float* __restrict__ pred,    // (B, N, 2) rows (x)
    const float* __restrict__ target,  // (B, N, 2) cols (y)
    float* __restrict__ out,
    float* __restrict__ ws)            // [0..63] per_batch, [64] flag
{
    const int b = blockIdx.x;
    const int j = threadIdx.x;

    __shared__ f32x2 xs[XSN];

    #pragma unroll
    for (int t = 0; t < NSEQ / LANES; ++t) {
        const int idx = t * LANES + j;
        xs[FRONT + idx] = reinterpret_cast<const f32x2*>(pred)[b * NSEQ + idx];
    }
    f32x2 nY[P];
    #pragma unroll
    for (int c = 0; c < P; ++c) {
        const f32x2 y = reinterpret_cast<const f32x2*>(target)[b * NSEQ + j * P + c];
        nY[c].x = -y.x; nY[c].y = -y.y;
    }
    __syncthreads();   // only barrier

    const float INF = __builtin_inff();
    float prev[P];
    #pragma unroll
    for (int c = 0; c < P; ++c) prev[c] = INF;
    float dg = INF;    // D[i-1][8j-1]; lane 0: INF forever

    // k = 0: lane 0, row 0, cumsum over its 8 cols (dg stays INF).
    if (j == 0) {
        const f32x2 x = xs[FRONT];
        float v = 0.f;
        #pragma unroll
        for (int c = 0; c < P; ++c) {
            const f32x2 d = x + nY[c];
            v += fabsf(d.x) + fabsf(d.y);
            prev[c] = v;
        }
    }

    // One step: v[c] = cost_c + min3(up=prev[c], diag=prev[c-1]|dg, left-chain).
    // INF identities fold row-0 cumsum in; guard masks prev[] commits.
    auto step = [&](f32x2 x, int k, bool guard) {
        float cost[P];
        #pragma unroll
        for (int c = 0; c < P; ++c) {
            const f32x2 d = pk_add(x, nY[c]);    // 1x v_pk_add_f32 (forced)
            cost[c] = fabsf(d.x) + fabsf(d.y);   // 1x v_add_f32 |a|,|b|
        }
        const float left = dpp_wshr1_inf(prev[P - 1]);
        float v[P];
        v[0] = cost[0] + fminf(fminf(prev[0], dg), left);
        float pm = prev[0];
        #pragma unroll
        for (int c = 1; c < P; ++c) {
            v[c] = cost[c] + fminf(fminf(prev[c], pm), v[c - 1]);
            pm = prev[c];
        }
        if (guard) {
            const bool act = (unsigned)(k - j) < (unsigned)NSEQ;
            #pragma unroll
            for (int c = 0; c < P; ++c) prev[c] = act ? v[c] : prev[c];
        } else {
            #pragma unroll
            for (int c = 0; c < P; ++c) prev[c] = v[c];
        }
        dg = left;
    };

    // 8 steps using ring Rr (rows k0..k0+7); prefetch rows k0+8..k0+15 into Nn.
    auto block8 = [&](int k0, f32x2 (&Rr)[8], f32x2 (&Nn)[8], bool guard) {
        #pragma unroll
        for (int d = 0; d < 8; ++d) Nn[d] = xs[FRONT + k0 + 8 + d - j];
        #pragma unroll
        for (int d = 0; d < 8; ++d) step(Rr[d], k0 + d, guard);
    };

    f32x2 R[8], N[8];
    #pragma unroll
    for (int d = 0; d < 8; ++d) R[d] = xs[FRONT + 1 + d - j];   // rows 1..8

    // 36 macro-blocks of 16 steps cover k = 1..576; ping-pong R/N.
    #pragma unroll 1
    for (int m = 0; m < 4; ++m) {          // ramp: k = 1..64
        const int k0 = 1 + m * 16;
        block8(k0, R, N, true);
        block8(k0 + 8, N, R, true);
    }
    #pragma unroll 1
    for (int m = 0; m < 27; ++m) {         // steady: k = 65..496
        const int k0 = 65 + m * 16;
        block8(k0, R, N, false);
        block8(k0 + 8, N, R, false);
    }
    #pragma unroll 1
    for (int m = 0; m < 5; ++m) {          // drain: k = 497..576
        const int k0 = 497 + m * 16;
        block8(k0, R, N, true);
        block8(k0 + 8, N, R, true);
    }

    // ---- fused mean reduction (last block to finish) ----
    float* per_batch = ws;
    unsigned* flag = reinterpret_cast<unsigned*>(ws + BATCH);
    if (j == LANES - 1) per_batch[b] = prev[P - 1];   // D[N-1][N-1]
    __threadfence();
    unsigned old = 0;
    if (j == 0) old = atomicAdd(flag, 1u);
    old = __shfl(old, 0);
    if (old == BATCH - 1) {
        __threadfence();
        float v = per_batch[j];
        #pragma unroll
        for (int off = 32; off >= 1; off >>= 1) v += __shfl_down(v, off);
        if (j == 0) out[0] = v * (1.0f / BATCH);
    }
}

extern "C" void kernel_launch(void* const* d_in, const int* in_sizes, int n_in,
                              void* d_out, int out_size, void* d_ws, size_t ws_size,
                              hipStream_t stream) {
    const float* pred   = (const float*)d_in[0];
    const float* target = (const float*)d_in[1];
    float* out = (float*)d_out;
    float* ws  = (float*)d_ws;

    hipMemsetAsync((char*)d_ws + BATCH * sizeof(float), 0, sizeof(unsigned), stream);
    dtw_fused<<<BATCH, LANES, 0, stream>>>(pred, target, out, ws);
}